// Round 2
// baseline (274.468 us; speedup 1.0000x reference)
//
#include <hip/hip_runtime.h>

// Problem constants (B=4, S=4096, D_MODEL=1024, H*Dk=H*Dv=1024)
#define M_TOT 16384
#define DM    1024

typedef unsigned short ushort_t;
typedef __bf16 bf16x8 __attribute__((ext_vector_type(8)));
typedef float  f32x4  __attribute__((ext_vector_type(4)));

__device__ __forceinline__ ushort_t f32_to_bf16(float f) {
    union { float f; unsigned u; } v; v.f = f;
    unsigned u = v.u;
    return (ushort_t)((u + 0x7fffu + ((u >> 16) & 1u)) >> 16);   // RNE
}
__device__ __forceinline__ float bf16_to_f32(ushort_t h) {
    union { unsigned u; float f; } v; v.u = ((unsigned)h) << 16;
    return v.f;
}

// async global->LDS, 16B per lane; LDS dest is wave-uniform base + lane*16
__device__ __forceinline__ void gload16(const ushort_t* g, ushort_t* l) {
    __builtin_amdgcn_global_load_lds(
        (const __attribute__((address_space(1))) unsigned int*)g,
        (__attribute__((address_space(3))) unsigned int*)l,
        16, 0, 0);
}

// ---------------- fused fp32 -> bf16 conversion ----------------
// x -> xb; Wv/Wg -> wcat with 16-row interleave (v rows p*32+r, g rows p*32+16+r)
// so that a 256-col GEMM tile pairs v/g fragments within one wave; Wo -> wob.
__global__ __launch_bounds__(256) void cvt_all(const float* __restrict__ x,
                                               const float* __restrict__ wv,
                                               const float* __restrict__ wg,
                                               const float* __restrict__ wo,
                                               ushort_t* __restrict__ xb,
                                               ushort_t* __restrict__ wcat,
                                               ushort_t* __restrict__ wob) {
    const long NX = (long)M_TOT * DM / 4, NW = (long)DM * DM / 4;
    long i = (long)blockIdx.x * 256 + threadIdx.x;     // float4 index
    const float* src; ushort_t* dst; long so, di;
    if (i < NX) {
        src = x; so = i; dst = xb; di = i;
    } else if (i < NX + NW) {
        long j = i - NX; src = wv; so = j;
        int row = (int)(j >> 8), c4 = (int)(j & 255);
        int orow = ((row >> 4) << 5) | (row & 15);
        dst = wcat; di = (long)orow * 256 + c4;
    } else if (i < NX + 2 * NW) {
        long j = i - NX - NW; src = wg; so = j;
        int row = (int)(j >> 8), c4 = (int)(j & 255);
        int orow = ((row >> 4) << 5) | 16 | (row & 15);
        dst = wcat; di = (long)orow * 256 + c4;
    } else {
        long j = i - NX - 2 * NW; src = wo; so = j; dst = wob; di = j;
    }
    const float4 v = ((const float4*)src)[so];
    ushort4 o;
    o.x = f32_to_bf16(v.x); o.y = f32_to_bf16(v.y);
    o.z = f32_to_bf16(v.z); o.w = f32_to_bf16(v.w);
    ((ushort4*)dst)[di] = o;
}

// ---------------- 256x256 fine-phase pipelined GEMM ----------------
// BM=BN=256, 512 threads (8 waves, 2M x 4N), per-wave 128x64, acc[8][4].
// K split into 32 "units" of K=32. LDS 128 KB = ring of 4 unit-slots
// (A 16KB + B 16KB each), fragment-tiled (1KB lane-linear frags, 0 bank
// conflicts, linear global_load_lds dest). Stage-ahead = 3 units.
// Per unit: 2 fine phases of 16 MFMA each (m201 template rhythm):
//   { ds_read frags ; issue 2 gload_lds ; sched_barrier ; s_barrier ;
//     setprio(1) ; 16 MFMA ; setprio(0) ; sched_barrier ; s_barrier }
// vmcnt(8) once per unit (never 0 in steady state); drain 8->4->0 at end.
// XCD map: xcd = flat&7 owns an 8-mblock stripe x all nblocks (L2-resident
// A panel + B panel). nbs = log2(n-blocks).
// EPI=0: silu-gate epilogue on interleaved v/g cols -> gated bf16 [M,1024]
// EPI=1: +bf16 residual -> pre bf16 [M,1024] (in-place over Xb is safe)
template<int EPI>
__global__ __launch_bounds__(512, 2) void gemm8p(
    const ushort_t* __restrict__ A,
    const ushort_t* __restrict__ B,
    const ushort_t* __restrict__ Xb,
    ushort_t* __restrict__ out,
    int nbs)
{
    extern __shared__ ushort_t lds[];   // 65536 ushorts = 128 KB

    const int flat = blockIdx.x;
    const int xcd  = flat & 7;
    const int ii   = flat >> 3;
    const int m0   = ((xcd << 3) + (ii >> nbs)) << 8;
    const int n0   = (ii & ((1 << nbs) - 1)) << 8;

    const int tid  = threadIdx.x;
    const int w    = tid >> 6;         // wave 0..7
    const int l    = tid & 63;
    const int wm   = w >> 2;           // 0..1 (M)
    const int wn   = w & 3;            // 0..3 (N)
    const int fr   = l & 15;
    const int quad = l >> 4;

    f32x4 acc[8][4];
    const f32x4 vzero = {0.f, 0.f, 0.f, 0.f};
#pragma unroll
    for (int i = 0; i < 8; ++i)
#pragma unroll
        for (int j = 0; j < 4; ++j) acc[i][j] = vzero;

    // staging sources: wave w stages A frags {w, w+8} (rows m0+w*16+fr,
    // m0+128+w*16+fr), lane k-chunk quad*8. Same for B with n0.
    const int sA0 = (m0 + w * 16 + fr) * DM + (quad << 3);
    const int sA1 = sA0 + 128 * DM;
    const int sB0 = (n0 + w * 16 + fr) * DM + (quad << 3);
    const int sB1 = sB0 + 128 * DM;

    auto stageA = [&](int u) {
        const int d  = (u & 3) * 8192 + w * 512;
        const int ko = u * 32;
        gload16(A + sA0 + ko, lds + d);
        gload16(A + sA1 + ko, lds + d + 4096);
    };
    auto stageB = [&](int u) {
        const int d  = 32768 + (u & 3) * 8192 + w * 512;
        const int ko = u * 32;
        gload16(B + sB0 + ko, lds + d);
        gload16(B + sB1 + ko, lds + d + 4096);
    };

    // fragment read bases (lane-linear 1KB frags)
    const int rA = wm * 4096 + l * 8;          // + slot*8192 + i*512
    const int rB = 32768 + wn * 2048 + l * 8;  // + slot*8192 + j*512

    // prologue: units 0,1,2 in flight (12 wave-loads); unit 0 landed
    stageA(0); stageB(0);
    stageA(1); stageB(1);
    stageA(2); stageB(2);
    asm volatile("s_waitcnt vmcnt(8)" ::: "memory");
    __builtin_amdgcn_s_barrier();

    for (int u = 0; u < 32; ++u) {
        const int sb = (u & 3) * 8192;
        bf16x8 bf[4], af[4];

        // ---- phase A: frags i=0..3 x j=0..3 ----
#pragma unroll
        for (int j = 0; j < 4; ++j) bf[j] = *(const bf16x8*)(lds + sb + rB + j * 512);
#pragma unroll
        for (int i = 0; i < 4; ++i) af[i] = *(const bf16x8*)(lds + sb + rA + i * 512);
        if (u < 29) stageA(u + 3);
        __builtin_amdgcn_sched_barrier(0);
        __builtin_amdgcn_s_barrier();
        __builtin_amdgcn_s_setprio(1);
#pragma unroll
        for (int j = 0; j < 4; ++j)
#pragma unroll
            for (int i = 0; i < 4; ++i)
                acc[i][j] = __builtin_amdgcn_mfma_f32_16x16x32_bf16(
                    af[i], bf[j], acc[i][j], 0, 0, 0);
        __builtin_amdgcn_s_setprio(0);
        __builtin_amdgcn_sched_barrier(0);
        __builtin_amdgcn_s_barrier();

        // ---- phase B: frags i=4..7 x j=0..3 (bf reused) ----
#pragma unroll
        for (int i = 0; i < 4; ++i) af[i] = *(const bf16x8*)(lds + sb + rA + (4 + i) * 512);
        if (u < 29) stageB(u + 3);
        if (u < 29)       { asm volatile("s_waitcnt vmcnt(8)" ::: "memory"); }
        else if (u == 29) { asm volatile("s_waitcnt vmcnt(4)" ::: "memory"); }
        else if (u == 30) { asm volatile("s_waitcnt vmcnt(0)" ::: "memory"); }
        __builtin_amdgcn_sched_barrier(0);
        __builtin_amdgcn_s_barrier();
        __builtin_amdgcn_s_setprio(1);
#pragma unroll
        for (int j = 0; j < 4; ++j)
#pragma unroll
            for (int i = 0; i < 4; ++i)
                acc[4 + i][j] = __builtin_amdgcn_mfma_f32_16x16x32_bf16(
                    af[i], bf[j], acc[4 + i][j], 0, 0, 0);
        __builtin_amdgcn_s_setprio(0);
        __builtin_amdgcn_sched_barrier(0);
        __builtin_amdgcn_s_barrier();
    }

    // epilogue; C/D layout: col = lane&15, row = quad*4 + r
    const int rowb = m0 + wm * 128;
    const int colb = n0 + wn * 64;
    if (EPI == 0) {
        // interleaved cat-cols: even frag = v, odd frag = g (same 16 v-cols)
#pragma unroll
        for (int i = 0; i < 8; ++i)
#pragma unroll
            for (int jp = 0; jp < 2; ++jp) {
                const int cb   = colb + jp * 32;
                const int vcol = ((cb >> 5) << 4) + fr;
#pragma unroll
                for (int r = 0; r < 4; ++r) {
                    const int row = rowb + i * 16 + quad * 4 + r;
                    float v = acc[i][2 * jp][r];
                    float g = acc[i][2 * jp + 1][r];
                    float gate = g / (1.0f + __expf(-g));   // silu
                    out[row * DM + vcol] = f32_to_bf16(v * gate);
                }
            }
    } else {
#pragma unroll
        for (int i = 0; i < 8; ++i)
#pragma unroll
            for (int j = 0; j < 4; ++j) {
                const int col = colb + j * 16 + fr;
#pragma unroll
                for (int r = 0; r < 4; ++r) {
                    const int row = rowb + i * 16 + quad * 4 + r;
                    float pre = acc[i][j][r] + bf16_to_f32(Xb[row * DM + col]);
                    out[row * DM + col] = f32_to_bf16(pre);
                }
            }
    }
}

// ---------------- LayerNorm over rows of 1024 ----------------
__global__ __launch_bounds__(256) void ln_rows(const ushort_t* __restrict__ pre,
                                               const float* __restrict__ gamma,
                                               const float* __restrict__ beta,
                                               float* __restrict__ out)
{
    const int row = blockIdx.x;
    const int tid = threadIdx.x;
    const int wave = tid >> 6, lane = tid & 63;

    ushort4 u = ((const ushort4*)(pre + row * DM))[tid];
    float p0 = bf16_to_f32(u.x), p1 = bf16_to_f32(u.y);
    float p2 = bf16_to_f32(u.z), p3 = bf16_to_f32(u.w);

    float s  = p0 + p1 + p2 + p3;
    float ss = p0 * p0 + p1 * p1 + p2 * p2 + p3 * p3;
#pragma unroll
    for (int off = 32; off > 0; off >>= 1) {
        s  += __shfl_down(s, off);
        ss += __shfl_down(ss, off);
    }
    __shared__ float red[8];
    __shared__ float mb[2];
    if (lane == 0) { red[wave] = s; red[4 + wave] = ss; }
    __syncthreads();
    if (tid == 0) {
        float S  = red[0] + red[1] + red[2] + red[3];
        float SS = red[4] + red[5] + red[6] + red[7];
        float mean = S * (1.0f / 1024.0f);
        float var  = SS * (1.0f / 1024.0f) - mean * mean;
        mb[0] = mean;
        mb[1] = rsqrtf(var + 1e-5f);
    }
    __syncthreads();
    const float mean = mb[0], rs = mb[1];

    float4 gm = ((const float4*)gamma)[tid];
    float4 bt = ((const float4*)beta)[tid];
    float4 o;
    o.x = (p0 - mean) * rs * gm.x + bt.x;
    o.y = (p1 - mean) * rs * gm.y + bt.y;
    o.z = (p2 - mean) * rs * gm.z + bt.z;
    o.w = (p3 - mean) * rs * gm.w + bt.w;
    ((float4*)(out + row * DM))[tid] = o;
}

// ---------------- launch ----------------
extern "C" void kernel_launch(void* const* d_in, const int* in_sizes, int n_in,
                              void* d_out, int out_size, void* d_ws, size_t ws_size,
                              hipStream_t stream) {
    // setup_inputs order: x, W_Q, W_K, W_V, W_g, W_alpha, W_O, ln_gamma, ln_beta
    const float* x     = (const float*)d_in[0];
    const float* WV    = (const float*)d_in[3];
    const float* WG    = (const float*)d_in[4];
    const float* WO    = (const float*)d_in[6];
    const float* gamma = (const float*)d_in[7];
    const float* beta  = (const float*)d_in[8];
    float* out = (float*)d_out;

    // ws layout: [0,32MB): x_bf16 (aliased as pre) | [32,64MB): gated
    //            [64,68MB): wcat (2048x1024 interleaved) | [68,70MB): wob
    char* ws = (char*)d_ws;
    ushort_t* xb    = (ushort_t*)ws;
    ushort_t* gated = (ushort_t*)(ws + (size_t)M_TOT * DM * 2);
    ushort_t* wcat  = (ushort_t*)(ws + (size_t)M_TOT * DM * 4);
    ushort_t* wob   = (ushort_t*)(ws + (size_t)M_TOT * DM * 4 + (size_t)2 * DM * DM * 2);
    ushort_t* pre   = xb;  // alias: in-place residual+store in gemm8p<1>

    static bool attr_set = false;
    if (!attr_set) {
        hipFuncSetAttribute((const void*)&gemm8p<0>,
                            hipFuncAttributeMaxDynamicSharedMemorySize, 131072);
        hipFuncSetAttribute((const void*)&gemm8p<1>,
                            hipFuncAttributeMaxDynamicSharedMemorySize, 131072);
        attr_set = true;
    }

    const int nCvt = (M_TOT * DM + 3 * DM * DM) / 4 / 256;
    cvt_all<<<nCvt, 256, 0, stream>>>(x, WV, WG, WO, xb, wcat, wob);

    // V&g cat-GEMM: M=16384, N=2048 -> 64 m-blocks x 8 n-blocks = 512
    gemm8p<0><<<512, 512, 131072, stream>>>(xb, wcat, nullptr, gated, 3);
    // O-proj: M=16384, N=1024 -> 64 m-blocks x 4 n-blocks = 256
    gemm8p<1><<<256, 512, 131072, stream>>>(gated, wob, xb, pre, 2);

    ln_rows<<<M_TOT, 256, 0, stream>>>(pre, gamma, beta, out);
}